// Round 1
// baseline (233.336 us; speedup 1.0000x reference)
//
#include <hip/hip_runtime.h>
#include <hip/hip_bf16.h>
#include <stdint.h>

typedef __bf16 bf16x8 __attribute__((ext_vector_type(8)));
typedef float f32x4 __attribute__((ext_vector_type(4)));
typedef unsigned short us4v __attribute__((ext_vector_type(4)));
typedef unsigned short us8v __attribute__((ext_vector_type(8)));

#define B_   2
#define T_   2048
#define C_   1024
#define NH_  16
#define HD_  64
#define SCALE_ 0.125f   // 1/sqrt(64), exact in bf16/fp32

__device__ __forceinline__ unsigned short f2bf(float f) {
  unsigned int u = __builtin_bit_cast(unsigned int, f);
  u += 0x7fffu + ((u >> 16) & 1u);           // RNE
  return (unsigned short)(u >> 16);
}

__device__ __forceinline__ void gload16(const void* g, void* l) {
  __builtin_amdgcn_global_load_lds(
      (const __attribute__((address_space(1))) unsigned int*)g,
      (__attribute__((address_space(3))) unsigned int*)l, 16, 0, 0);
}

__device__ __forceinline__ f32x4 mfma16(bf16x8 a, bf16x8 b, f32x4 c) {
  return __builtin_amdgcn_mfma_f32_16x16x32_bf16(a, b, c, 0, 0, 0);
}

// ---------------- cast / transpose ----------------
__global__ __launch_bounds__(256) void cast_x_kernel(const float4* __restrict__ in,
                                                     us4v* __restrict__ out) {
  int i = blockIdx.x * 256 + threadIdx.x;
  float4 f = in[i];
  us4v o; o[0] = f2bf(f.x); o[1] = f2bf(f.y); o[2] = f2bf(f.z); o[3] = f2bf(f.w);
  out[i] = o;
}

// w: (K x N) fp32 row-major  ->  wT: (N x K) bf16 row-major
__global__ __launch_bounds__(256) void transpose_cast_kernel(const float* __restrict__ w,
                                                             unsigned short* __restrict__ wT,
                                                             int K, int N) {
  __shared__ float tile[32][33];
  int n0 = blockIdx.x * 32, k0 = blockIdx.y * 32;
  int tx = threadIdx.x, ty = threadIdx.y;   // 32 x 8
  #pragma unroll
  for (int i = 0; i < 4; ++i)
    tile[ty + 8*i][tx] = w[(size_t)(k0 + ty + 8*i) * N + n0 + tx];
  __syncthreads();
  #pragma unroll
  for (int i = 0; i < 4; ++i)
    wT[(size_t)(n0 + ty + 8*i) * K + k0 + tx] = f2bf(tile[tx][ty + 8*i]);
}

// ---------------- GEMM core: C[m,n] = sum_k A[m,k] * Bt[n,k] ----------------
// A: M x K bf16 row-major, Bt: N x K bf16 row-major. Tile 128x128, BK=64.
// LDS tiles [128][64] bf16 (128B rows), XOR slot swizzle: phys_slot = log_slot ^ (row&7).
__device__ __forceinline__ void gemm_core(const unsigned short* __restrict__ A,
                                          const unsigned short* __restrict__ Bt,
                                          int K, int m0, int n0,
                                          unsigned short* lA, unsigned short* lB,
                                          f32x4 acc[4][4]) {
  const int t = threadIdx.x;
  const int lane = t & 63, w = t >> 6;
  const int wm = w >> 1, wn = w & 1;
  const int g = lane >> 4, r16 = lane & 15;
  #pragma unroll
  for (int i = 0; i < 4; ++i)
    #pragma unroll
    for (int j = 0; j < 4; ++j) acc[i][j] = (f32x4){0.f, 0.f, 0.f, 0.f};

  for (int k0 = 0; k0 < K; k0 += 64) {
    #pragma unroll
    for (int i = 0; i < 4; ++i) {
      int slot = i * 256 + t;
      int r = slot >> 3, p = slot & 7;
      int q = p ^ (r & 7);                 // inverse-swizzled global source
      gload16(A  + (size_t)(m0 + r) * K + k0 + q * 8, lA + slot * 8);
      gload16(Bt + (size_t)(n0 + r) * K + k0 + q * 8, lB + slot * 8);
    }
    asm volatile("s_waitcnt vmcnt(0)" ::: "memory");
    __syncthreads();

    bf16x8 af[4][2], bfr[4][2];
    #pragma unroll
    for (int mi = 0; mi < 4; ++mi)
      #pragma unroll
      for (int kk = 0; kk < 2; ++kk) {
        int r = wm * 64 + mi * 16 + r16;
        int ps = (kk * 4 + g) ^ (r & 7);
        af[mi][kk] = *(const bf16x8*)(lA + r * 64 + ps * 8);
      }
    #pragma unroll
    for (int ni = 0; ni < 4; ++ni)
      #pragma unroll
      for (int kk = 0; kk < 2; ++kk) {
        int r = wn * 64 + ni * 16 + r16;
        int ps = (kk * 4 + g) ^ (r & 7);
        bfr[ni][kk] = *(const bf16x8*)(lB + r * 64 + ps * 8);
      }
    #pragma unroll
    for (int mi = 0; mi < 4; ++mi)
      #pragma unroll
      for (int ni = 0; ni < 4; ++ni)
        #pragma unroll
        for (int kk = 0; kk < 2; ++kk)
          acc[mi][ni] = mfma16(af[mi][kk], bfr[ni][kk], acc[mi][ni]);
    __syncthreads();
  }
}

// ---------------- GEMM 1: qkv = x @ w_qkv, scatter into Q,K,V (B,NH,T,HD) ----------------
__global__ __launch_bounds__(256) void gemm_qkv_kernel(const unsigned short* __restrict__ xb,
                                                       const unsigned short* __restrict__ wT,
                                                       unsigned short* __restrict__ qb,
                                                       unsigned short* __restrict__ kb,
                                                       unsigned short* __restrict__ vb) {
  __shared__ unsigned short lA[128 * 64];
  __shared__ unsigned short lB[128 * 64];
  f32x4 acc[4][4];
  const int m0 = blockIdx.y * 128, n0 = blockIdx.x * 128;
  gemm_core(xb, wT, C_, m0, n0, lA, lB, acc);
  const int t = threadIdx.x, lane = t & 63, w = t >> 6;
  const int wm = w >> 1, wn = w & 1, g = lane >> 4, r16 = lane & 15;
  #pragma unroll
  for (int mi = 0; mi < 4; ++mi)
    #pragma unroll
    for (int ni = 0; ni < 4; ++ni)
      #pragma unroll
      for (int j = 0; j < 4; ++j) {
        int gm = m0 + wm * 64 + mi * 16 + g * 4 + j;     // row = (lane>>4)*4 + reg (m89)
        int gn = n0 + wn * 64 + ni * 16 + r16;           // col = lane&15
        int b = gm >> 11, tt = gm & 2047;
        int s = gn >> 10, rem = gn & 1023;
        int h = rem >> 6, d = rem & 63;
        unsigned short val = f2bf(acc[mi][ni][j]);
        size_t idx = ((size_t)(b * NH_ + h) * T_ + tt) * HD_ + d;
        if (s == 0)      qb[idx] = val;
        else if (s == 1) kb[idx] = val;
        else             vb[idx] = val;
      }
}

// ---------------- GEMM 2: out = attn_out @ w_proj (fp32 out) ----------------
__global__ __launch_bounds__(256) void gemm_proj_kernel(const unsigned short* __restrict__ ab,
                                                        const unsigned short* __restrict__ wT,
                                                        float* __restrict__ out) {
  __shared__ unsigned short lA[128 * 64];
  __shared__ unsigned short lB[128 * 64];
  f32x4 acc[4][4];
  const int m0 = blockIdx.y * 128, n0 = blockIdx.x * 128;
  gemm_core(ab, wT, C_, m0, n0, lA, lB, acc);
  const int t = threadIdx.x, lane = t & 63, w = t >> 6;
  const int wm = w >> 1, wn = w & 1, g = lane >> 4, r16 = lane & 15;
  #pragma unroll
  for (int mi = 0; mi < 4; ++mi)
    #pragma unroll
    for (int ni = 0; ni < 4; ++ni)
      #pragma unroll
      for (int j = 0; j < 4; ++j) {
        int gm = m0 + wm * 64 + mi * 16 + g * 4 + j;
        int gn = n0 + wn * 64 + ni * 16 + r16;
        out[(size_t)gm * C_ + gn] = acc[mi][ni][j];
      }
}

// ---------------- Flash attention ----------------
// grid (T/64, B*NH), 256 threads. Wave w handles Q rows [qt0+16w, qt0+16w+16).
__global__ __launch_bounds__(256) void attn_kernel(const unsigned short* __restrict__ qb,
                                                   const unsigned short* __restrict__ kb,
                                                   const unsigned short* __restrict__ vb,
                                                   unsigned short* __restrict__ ao) {
  __shared__ unsigned short Ks[64 * 64];   // [kv][d], swizzled slots
  __shared__ unsigned short Vs[64 * 64];   // [d][kv] (transposed), swizzled bytes
  __shared__ unsigned short Ps[4 * 16 * 64]; // per-wave P tile, swizzled bytes

  const int bh = blockIdx.y;
  const int qt0 = blockIdx.x * 64;
  const int t = threadIdx.x, lane = t & 63, w = t >> 6;
  const int g = lane >> 4, r16 = lane & 15;
  const unsigned short* Q = qb + (size_t)bh * T_ * HD_;
  const unsigned short* K = kb + (size_t)bh * T_ * HD_;
  const unsigned short* V = vb + (size_t)bh * T_ * HD_;

  // Q fragments (A-operand), held for the whole kernel
  bf16x8 qf[2];
  {
    int qrow = qt0 + w * 16 + r16;
    #pragma unroll
    for (int kk = 0; kk < 2; ++kk)
      qf[kk] = *(const bf16x8*)(Q + (size_t)qrow * HD_ + kk * 32 + g * 8);
  }

  f32x4 o[4];
  #pragma unroll
  for (int c = 0; c < 4; ++c) o[c] = (f32x4){0.f, 0.f, 0.f, 0.f};
  float mrun[4], lrun[4];
  #pragma unroll
  for (int j = 0; j < 4; ++j) { mrun[j] = -__builtin_inff(); lrun[j] = 0.f; }

  const int ntiles = qt0 / 64 + 1;
  for (int it = 0; it < ntiles; ++it) {
    const int kv0 = it * 64;
    // stage K tile [64][64] via global_load_lds, pre-swizzled source
    #pragma unroll
    for (int i = 0; i < 2; ++i) {
      int slot = i * 256 + t;
      int r = slot >> 3, p = slot & 7;
      int q = p ^ (r & 7);
      gload16(K + (size_t)(kv0 + r) * HD_ + q * 8, Ks + slot * 8);
    }
    // stage V transposed: Vs[d][kv], swizzled byte ^= (d&7)<<4
    #pragma unroll
    for (int i = 0; i < 2; ++i) {
      int slot = i * 256 + t;
      int s = slot >> 3, d0 = (slot & 7) * 8;
      us8v vv = *(const us8v*)(V + (size_t)(kv0 + s) * HD_ + d0);
      #pragma unroll
      for (int jj = 0; jj < 8; ++jj) {
        int d = d0 + jj;
        int pb = (s * 2) ^ ((d & 7) << 4);
        Vs[d * 64 + (pb >> 1)] = vv[jj];
      }
    }
    asm volatile("s_waitcnt vmcnt(0)" ::: "memory");
    __syncthreads();

    // S = Q @ K^T  (per wave: 16 x 64)
    f32x4 s4[4];
    #pragma unroll
    for (int c = 0; c < 4; ++c) s4[c] = (f32x4){0.f, 0.f, 0.f, 0.f};
    #pragma unroll
    for (int c = 0; c < 4; ++c)
      #pragma unroll
      for (int kk = 0; kk < 2; ++kk) {
        int r = c * 16 + r16;
        int ps = (kk * 4 + g) ^ (r & 7);
        bf16x8 kf = *(const bf16x8*)(Ks + r * 64 + ps * 8);
        s4[c] = mfma16(qf[kk], kf, s4[c]);
      }
    #pragma unroll
    for (int c = 0; c < 4; ++c)
      #pragma unroll
      for (int j = 0; j < 4; ++j) s4[c][j] *= SCALE_;
    if (it == ntiles - 1) {   // diagonal tile: mask n > m
      #pragma unroll
      for (int c = 0; c < 4; ++c)
        #pragma unroll
        for (int j = 0; j < 4; ++j) {
          int n = c * 16 + r16, m = w * 16 + g * 4 + j;
          if (n > m) s4[c][j] = -1e30f;
        }
    }
    // online softmax (rows live on 16-lane groups: lane = g*16 + r16)
    float pm[4];
    #pragma unroll
    for (int j = 0; j < 4; ++j)
      pm[j] = fmaxf(fmaxf(s4[0][j], s4[1][j]), fmaxf(s4[2][j], s4[3][j]));
    #pragma unroll
    for (int msk = 1; msk < 16; msk <<= 1)
      #pragma unroll
      for (int j = 0; j < 4; ++j) pm[j] = fmaxf(pm[j], __shfl_xor(pm[j], msk));
    float alpha[4];
    #pragma unroll
    for (int j = 0; j < 4; ++j) {
      float mn = fmaxf(mrun[j], pm[j]);
      alpha[j] = __expf(mrun[j] - mn);
      mrun[j] = mn;
    }
    float rs[4] = {0.f, 0.f, 0.f, 0.f};
    #pragma unroll
    for (int c = 0; c < 4; ++c)
      #pragma unroll
      for (int j = 0; j < 4; ++j) {
        float p = __expf(s4[c][j] - mrun[j]);
        s4[c][j] = p;
        rs[j] += p;
      }
    #pragma unroll
    for (int msk = 1; msk < 16; msk <<= 1)
      #pragma unroll
      for (int j = 0; j < 4; ++j) rs[j] += __shfl_xor(rs[j], msk);
    #pragma unroll
    for (int j = 0; j < 4; ++j) lrun[j] = lrun[j] * alpha[j] + rs[j];
    #pragma unroll
    for (int c = 0; c < 4; ++c)
      #pragma unroll
      for (int j = 0; j < 4; ++j) o[c][j] *= alpha[j];

    // P -> LDS (bf16, swizzled), per-wave region; same-wave write->read
    unsigned short* Pw = Ps + w * 16 * 64;
    #pragma unroll
    for (int c = 0; c < 4; ++c)
      #pragma unroll
      for (int j = 0; j < 4; ++j) {
        int row = g * 4 + j, col = c * 16 + r16;
        int pb = (col * 2) ^ ((row & 7) << 4);
        Pw[row * 64 + (pb >> 1)] = f2bf(s4[c][j]);
      }
    // O += P @ V
    bf16x8 pf[2];
    #pragma unroll
    for (int kk = 0; kk < 2; ++kk) {
      int pb = (kk * 64 + g * 16) ^ ((r16 & 7) << 4);
      pf[kk] = *(const bf16x8*)(Pw + r16 * 64 + (pb >> 1));
    }
    #pragma unroll
    for (int c = 0; c < 4; ++c)
      #pragma unroll
      for (int kk = 0; kk < 2; ++kk) {
        int rv = c * 16 + r16;
        int pb = (kk * 64 + g * 16) ^ ((rv & 7) << 4);
        bf16x8 vf = *(const bf16x8*)(Vs + rv * 64 + (pb >> 1));
        o[c] = mfma16(pf[kk], vf, o[c]);
      }
    __syncthreads();   // protect Ks/Vs before next tile's staging
  }

  // epilogue: ao (B,T,C) bf16
  const int b = bh >> 4, h = bh & 15;
  #pragma unroll
  for (int c = 0; c < 4; ++c)
    #pragma unroll
    for (int j = 0; j < 4; ++j) {
      int row = qt0 + w * 16 + g * 4 + j;
      int col = h * 64 + c * 16 + r16;
      float val = o[c][j] / lrun[j];
      ao[((size_t)b * T_ + row) * C_ + col] = f2bf(val);
    }
}

// ---------------- launch ----------------
extern "C" void kernel_launch(void* const* d_in, const int* in_sizes, int n_in,
                              void* d_out, int out_size, void* d_ws, size_t ws_size,
                              hipStream_t stream) {
  const float* x      = (const float*)d_in[0];
  const float* w_qkv  = (const float*)d_in[1];
  const float* w_proj = (const float*)d_in[2];
  float* out = (float*)d_out;
  char* ws = (char*)d_ws;

  unsigned short* xb     = (unsigned short*)(ws);              // 8,388,608 B (reused as ao)
  unsigned short* wqkvT  = (unsigned short*)(ws + 8388608);    // 6,291,456 B
  unsigned short* wprojT = (unsigned short*)(ws + 14680064);   // 2,097,152 B
  unsigned short* qb     = (unsigned short*)(ws + 16777216);   // 8,388,608 B
  unsigned short* kb     = (unsigned short*)(ws + 25165824);   // 8,388,608 B
  unsigned short* vb     = (unsigned short*)(ws + 33554432);   // 8,388,608 B
  unsigned short* ao     = xb;  // xb is dead after gemm_qkv; reuse for attention output

  cast_x_kernel<<<4096, 256, 0, stream>>>((const float4*)x, (us4v*)xb);
  transpose_cast_kernel<<<dim3(3 * C_ / 32, C_ / 32), dim3(32, 8), 0, stream>>>(
      w_qkv, wqkvT, C_, 3 * C_);
  transpose_cast_kernel<<<dim3(C_ / 32, C_ / 32), dim3(32, 8), 0, stream>>>(
      w_proj, wprojT, C_, C_);
  gemm_qkv_kernel<<<dim3(3 * C_ / 128, (B_ * T_) / 128), 256, 0, stream>>>(
      xb, wqkvT, qb, kb, vb);
  attn_kernel<<<dim3(T_ / 64, B_ * NH_), 256, 0, stream>>>(qb, kb, vb, ao);
  gemm_proj_kernel<<<dim3(C_ / 128, (B_ * T_) / 128), 256, 0, stream>>>(
      ao, wprojT, out);
}

// Round 3
// 165.340 us; speedup vs baseline: 1.4113x; 1.4113x over previous
//
#include <hip/hip_runtime.h>
#include <hip/hip_bf16.h>
#include <stdint.h>

typedef __bf16 bf16x8 __attribute__((ext_vector_type(8)));
typedef float f32x4 __attribute__((ext_vector_type(4)));
typedef unsigned short us4v __attribute__((ext_vector_type(4)));
typedef unsigned short us8v __attribute__((ext_vector_type(8)));

#define B_   2
#define T_   2048
#define C_   1024
#define NH_  16
#define HD_  64

__device__ __forceinline__ unsigned short f2bf(float f) {
  unsigned int u = __builtin_bit_cast(unsigned int, f);
  u += 0x7fffu + ((u >> 16) & 1u);           // RNE
  return (unsigned short)(u >> 16);
}
__device__ __forceinline__ float bf2f(unsigned short u) {
  unsigned int x = ((unsigned int)u) << 16;
  return __builtin_bit_cast(float, x);
}

__device__ __forceinline__ void gload16(const void* g, void* l) {
  __builtin_amdgcn_global_load_lds(
      (const __attribute__((address_space(1))) unsigned int*)g,
      (__attribute__((address_space(3))) unsigned int*)l, 16, 0, 0);
}

__device__ __forceinline__ f32x4 mfma16(bf16x8 a, bf16x8 b, f32x4 c) {
  return __builtin_amdgcn_mfma_f32_16x16x32_bf16(a, b, c, 0, 0, 0);
}

// ---------------- cast / transpose ----------------
__global__ __launch_bounds__(256) void cast_x_kernel(const float4* __restrict__ in,
                                                     us4v* __restrict__ out) {
  int i = blockIdx.x * 256 + threadIdx.x;
  float4 f = in[i];
  us4v o; o[0] = f2bf(f.x); o[1] = f2bf(f.y); o[2] = f2bf(f.z); o[3] = f2bf(f.w);
  out[i] = o;
}

// w: (K x N) fp32 row-major  ->  wT: (N x K) bf16 row-major
__global__ __launch_bounds__(256) void transpose_cast_kernel(const float* __restrict__ w,
                                                             unsigned short* __restrict__ wT,
                                                             int K, int N) {
  __shared__ float tile[32][33];
  int n0 = blockIdx.x * 32, k0 = blockIdx.y * 32;
  int tx = threadIdx.x, ty = threadIdx.y;   // 32 x 8
  #pragma unroll
  for (int i = 0; i < 4; ++i)
    tile[ty + 8*i][tx] = w[(size_t)(k0 + ty + 8*i) * N + n0 + tx];
  __syncthreads();
  #pragma unroll
  for (int i = 0; i < 4; ++i)
    wT[(size_t)(n0 + ty + 8*i) * K + k0 + tx] = f2bf(tile[tx][ty + 8*i]);
}

// ---------------- GEMM core (verified round 0) ----------------
__device__ __forceinline__ void gemm_core(const unsigned short* __restrict__ A,
                                          const unsigned short* __restrict__ Bt,
                                          int K, int m0, int n0,
                                          unsigned short* lA, unsigned short* lB,
                                          f32x4 acc[4][4]) {
  const int t = threadIdx.x;
  const int lane = t & 63, w = t >> 6;
  const int wm = w >> 1, wn = w & 1;
  const int g = lane >> 4, r16 = lane & 15;
  #pragma unroll
  for (int i = 0; i < 4; ++i)
    #pragma unroll
    for (int j = 0; j < 4; ++j) acc[i][j] = (f32x4){0.f, 0.f, 0.f, 0.f};

  for (int k0 = 0; k0 < K; k0 += 64) {
    #pragma unroll
    for (int i = 0; i < 4; ++i) {
      int slot = i * 256 + t;
      int r = slot >> 3, p = slot & 7;
      int q = p ^ (r & 7);
      gload16(A  + (size_t)(m0 + r) * K + k0 + q * 8, lA + slot * 8);
      gload16(Bt + (size_t)(n0 + r) * K + k0 + q * 8, lB + slot * 8);
    }
    asm volatile("s_waitcnt vmcnt(0)" ::: "memory");
    __syncthreads();

    bf16x8 af[4][2], bfr[4][2];
    #pragma unroll
    for (int mi = 0; mi < 4; ++mi)
      #pragma unroll
      for (int kk = 0; kk < 2; ++kk) {
        int r = wm * 64 + mi * 16 + r16;
        int ps = (kk * 4 + g) ^ (r & 7);
        af[mi][kk] = *(const bf16x8*)(lA + r * 64 + ps * 8);
      }
    #pragma unroll
    for (int ni = 0; ni < 4; ++ni)
      #pragma unroll
      for (int kk = 0; kk < 2; ++kk) {
        int r = wn * 64 + ni * 16 + r16;
        int ps = (kk * 4 + g) ^ (r & 7);
        bfr[ni][kk] = *(const bf16x8*)(lB + r * 64 + ps * 8);
      }
    #pragma unroll
    for (int mi = 0; mi < 4; ++mi)
      #pragma unroll
      for (int ni = 0; ni < 4; ++ni)
        #pragma unroll
        for (int kk = 0; kk < 2; ++kk)
          acc[mi][ni] = mfma16(af[mi][kk], bfr[ni][kk], acc[mi][ni]);
    __syncthreads();
  }
}

__global__ __launch_bounds__(256) void gemm_qkv_kernel(const unsigned short* __restrict__ xb,
                                                       const unsigned short* __restrict__ wT,
                                                       unsigned short* __restrict__ qb,
                                                       unsigned short* __restrict__ kb,
                                                       unsigned short* __restrict__ vb) {
  __shared__ unsigned short lA[128 * 64];
  __shared__ unsigned short lB[128 * 64];
  f32x4 acc[4][4];
  const int m0 = blockIdx.y * 128, n0 = blockIdx.x * 128;
  gemm_core(xb, wT, C_, m0, n0, lA, lB, acc);
  const int t = threadIdx.x, lane = t & 63, w = t >> 6;
  const int wm = w >> 1, wn = w & 1, g = lane >> 4, r16 = lane & 15;
  #pragma unroll
  for (int mi = 0; mi < 4; ++mi)
    #pragma unroll
    for (int ni = 0; ni < 4; ++ni)
      #pragma unroll
      for (int j = 0; j < 4; ++j) {
        int gm = m0 + wm * 64 + mi * 16 + g * 4 + j;
        int gn = n0 + wn * 64 + ni * 16 + r16;
        int b = gm >> 11, tt = gm & 2047;
        int s = gn >> 10, rem = gn & 1023;
        int h = rem >> 6, d = rem & 63;
        unsigned short val = f2bf(acc[mi][ni][j]);
        size_t idx = ((size_t)(b * NH_ + h) * T_ + tt) * HD_ + d;
        if (s == 0)      qb[idx] = val;
        else if (s == 1) kb[idx] = val;
        else             vb[idx] = val;
      }
}

__global__ __launch_bounds__(256) void gemm_proj_kernel(const unsigned short* __restrict__ ab,
                                                        const unsigned short* __restrict__ wT,
                                                        float* __restrict__ out) {
  __shared__ unsigned short lA[128 * 64];
  __shared__ unsigned short lB[128 * 64];
  f32x4 acc[4][4];
  const int m0 = blockIdx.y * 128, n0 = blockIdx.x * 128;
  gemm_core(ab, wT, C_, m0, n0, lA, lB, acc);
  const int t = threadIdx.x, lane = t & 63, w = t >> 6;
  const int wm = w >> 1, wn = w & 1, g = lane >> 4, r16 = lane & 15;
  #pragma unroll
  for (int mi = 0; mi < 4; ++mi)
    #pragma unroll
    for (int ni = 0; ni < 4; ++ni)
      #pragma unroll
      for (int j = 0; j < 4; ++j) {
        int gm = m0 + wm * 64 + mi * 16 + g * 4 + j;
        int gn = n0 + wn * 64 + ni * 16 + r16;
        out[(size_t)gm * C_ + gn] = acc[mi][ni][j];
      }
}

// ---------------- Flash attention ----------------
// Balanced pairs: block (pairIdx, bh). Waves 0-3 -> q-tile pairIdx (short),
// waves 4-7 -> q-tile 31-pairIdx (long). Per-wave math identical to the
// verified round-0 kernel. Double-buffered K/V, one barrier per iteration.
// LDS map (us units): K0 [0,4096) K1 [4096,8192) V0 [8192,12288) V1 [12288,16384)
//                     P/epi: per-wave 1088 us at 16384 + w*1088.
__global__ __launch_bounds__(512) void attn_kernel(const unsigned short* __restrict__ qb,
                                                   const unsigned short* __restrict__ kb,
                                                   const unsigned short* __restrict__ vb,
                                                   unsigned short* __restrict__ ao) {
  __shared__ unsigned short LDS[25088];
  const int pairIdx = blockIdx.x, bh = blockIdx.y;
  const int t = threadIdx.x, lane = t & 63, w = t >> 6;
  const int g = lane >> 4, r16 = lane & 15;
  const int ws = w & 3, sel = w >> 2;
  const int qt0 = (sel ? (31 - pairIdx) : pairIdx) * 64;
  const int myNt = (qt0 >> 6) + 1;
  const int ntMax = (32 - pairIdx);

  const unsigned short* Q  = qb + (size_t)bh * (T_ * HD_);
  const unsigned short* Kp = kb + (size_t)bh * (T_ * HD_);
  const unsigned short* Vp = vb + (size_t)bh * (T_ * HD_);

  // Q fragments, pre-scaled by 1/8 (exact in bf16)
  bf16x8 qf[2];
  {
    int qrow = qt0 + ws * 16 + r16;
    #pragma unroll
    for (int kk = 0; kk < 2; ++kk) {
      us8v raw = *(const us8v*)(Q + (size_t)qrow * HD_ + kk * 32 + g * 8);
      bf16x8 qv;
      #pragma unroll
      for (int j = 0; j < 8; ++j) qv[j] = (__bf16)(bf2f(raw[j]) * 0.125f);
      qf[kk] = qv;
    }
  }

  f32x4 o[4];
  #pragma unroll
  for (int c = 0; c < 4; ++c) o[c] = (f32x4){0.f, 0.f, 0.f, 0.f};
  float mrun[4], lrun[4];
  #pragma unroll
  for (int j = 0; j < 4; ++j) { mrun[j] = -__builtin_inff(); lrun[j] = 0.f; }

  // staging indices (per thread, constant)
  const int kr = t >> 3, kp = (t & 7) ^ (kr & 7);            // K: row, swizzled 8-us granule
  const int sV = t >> 3, d0V = (t & 7) * 8;                  // V: row, d-octet
  unsigned short* Pw = LDS + 16384 + w * 1088;

  // prologue: issue tile-0 loads
  gload16(Kp + (size_t)kr * HD_ + kp * 8, LDS + t * 8);
  us8v vrA = *(const us8v*)(Vp + (size_t)sV * HD_ + d0V);
  us8v vrB;

  for (int it = 0; it < ntMax; ++it) {
    const int cur = it & 1;
    const unsigned short* Kl = LDS + cur * 4096;
    unsigned short* Vs = LDS + 8192 + cur * 4096;

    asm volatile("s_waitcnt vmcnt(0)" ::: "memory");   // K[it] in LDS, V[it] in regs
    {
      us8v vv = cur ? vrB : vrA;
      #pragma unroll
      for (int jj = 0; jj < 8; ++jj) {
        int d = d0V + jj;
        Vs[d * 64 + (sV ^ ((d & 7) << 3))] = vv[jj];
      }
    }
    __syncthreads();

    if (it + 1 < ntMax) {    // issue next-tile loads (land in buf cur^1)
      const int kv0n = (it + 1) * 64;
      gload16(Kp + (size_t)(kv0n + kr) * HD_ + kp * 8, LDS + (cur ^ 1) * 4096 + t * 8);
      us8v nv = *(const us8v*)(Vp + (size_t)(kv0n + sV) * HD_ + d0V);
      if (cur) vrA = nv; else vrB = nv;
    }

    if (it < myNt) {
      const int kv0 = it * 64;
      // S = Q @ K^T  (per wave: 16 x 64); rows m = g*4+j, cols n = c*16+r16
      f32x4 s4[4];
      #pragma unroll
      for (int c = 0; c < 4; ++c) s4[c] = (f32x4){0.f, 0.f, 0.f, 0.f};
      #pragma unroll
      for (int c = 0; c < 4; ++c)
        #pragma unroll
        for (int kk = 0; kk < 2; ++kk) {
          int r = c * 16 + r16;
          int ps = (kk * 4 + g) ^ (r & 7);
          bf16x8 kf = *(const bf16x8*)(Kl + r * 64 + ps * 8);
          s4[c] = mfma16(qf[kk], kf, s4[c]);
        }
      if (it == myNt - 1) {   // diagonal tile: mask n > m (kv0 == qt0 here)
        #pragma unroll
        for (int c = 0; c < 4; ++c)
          #pragma unroll
          for (int j = 0; j < 4; ++j) {
            int n = c * 16 + r16, m = ws * 16 + g * 4 + j;
            if (n > m) s4[c][j] = -1e30f;
          }
      }
      // online softmax (rows spread across r16 within each 16-lane group)
      float pm[4];
      #pragma unroll
      for (int j = 0; j < 4; ++j)
        pm[j] = fmaxf(fmaxf(s4[0][j], s4[1][j]), fmaxf(s4[2][j], s4[3][j]));
      #pragma unroll
      for (int msk = 1; msk < 16; msk <<= 1)
        #pragma unroll
        for (int j = 0; j < 4; ++j) pm[j] = fmaxf(pm[j], __shfl_xor(pm[j], msk));
      float alpha[4];
      #pragma unroll
      for (int j = 0; j < 4; ++j) {
        float mn = fmaxf(mrun[j], pm[j]);
        alpha[j] = __expf(mrun[j] - mn);
        mrun[j] = mn;
      }
      float rs[4] = {0.f, 0.f, 0.f, 0.f};
      #pragma unroll
      for (int c = 0; c < 4; ++c)
        #pragma unroll
        for (int j = 0; j < 4; ++j) {
          float p = __expf(s4[c][j] - mrun[j]);
          s4[c][j] = p;
          rs[j] += p;
        }
      #pragma unroll
      for (int msk = 1; msk < 16; msk <<= 1)
        #pragma unroll
        for (int j = 0; j < 4; ++j) rs[j] += __shfl_xor(rs[j], msk);
      #pragma unroll
      for (int j = 0; j < 4; ++j) lrun[j] = lrun[j] * alpha[j] + rs[j];
      #pragma unroll
      for (int c = 0; c < 4; ++c)
        #pragma unroll
        for (int j = 0; j < 4; ++j) o[c][j] *= alpha[j];

      // P -> per-wave LDS (swizzled), same-wave write->read
      #pragma unroll
      for (int c = 0; c < 4; ++c)
        #pragma unroll
        for (int j = 0; j < 4; ++j) {
          int row = g * 4 + j, col = c * 16 + r16;
          int pb = (col * 2) ^ ((row & 7) << 4);
          Pw[row * 64 + (pb >> 1)] = f2bf(s4[c][j]);
        }
      bf16x8 pf[2];
      #pragma unroll
      for (int kk = 0; kk < 2; ++kk) {
        int pb = (kk * 64 + g * 16) ^ ((r16 & 7) << 4);
        pf[kk] = *(const bf16x8*)(Pw + r16 * 64 + (pb >> 1));
      }
      #pragma unroll
      for (int c = 0; c < 4; ++c)
        #pragma unroll
        for (int kk = 0; kk < 2; ++kk) {
          int rv = c * 16 + r16;
          int pb = (kk * 64 + g * 16) ^ ((rv & 7) << 4);
          bf16x8 vf = *(const bf16x8*)(Vs + rv * 64 + (pb >> 1));
          o[c] = mfma16(pf[kk], vf, o[c]);
        }
    }
  }

  // epilogue: per-wave LDS transpose -> coalesced bf16 store
  unsigned short* ep = Pw;   // 16 rows x stride 68
  #pragma unroll
  for (int c = 0; c < 4; ++c)
    #pragma unroll
    for (int j = 0; j < 4; ++j) {
      int row = g * 4 + j;
      ep[row * 68 + c * 16 + r16] = f2bf(o[c][j] / lrun[j]);
    }
  asm volatile("s_waitcnt lgkmcnt(0)" ::: "memory");
  __builtin_amdgcn_sched_barrier(0);
  {
    int q = lane >> 2, seg = lane & 3;
    const unsigned short* epr = ep + q * 68 + seg * 16;
    us4v a0 = *(const us4v*)(epr + 0);
    us4v a1 = *(const us4v*)(epr + 4);
    us4v a2 = *(const us4v*)(epr + 8);
    us4v a3 = *(const us4v*)(epr + 12);
    us8v o0 = {a0[0],a0[1],a0[2],a0[3],a1[0],a1[1],a1[2],a1[3]};
    us8v o1 = {a2[0],a2[1],a2[2],a2[3],a3[0],a3[1],a3[2],a3[3]};
    size_t rowg = (size_t)(bh >> 4) * T_ + qt0 + ws * 16 + q;
    int colg = (bh & 15) * 64 + seg * 16;
    *(us8v*)(ao + rowg * C_ + colg)     = o0;
    *(us8v*)(ao + rowg * C_ + colg + 8) = o1;
  }
}

// ---------------- launch ----------------
extern "C" void kernel_launch(void* const* d_in, const int* in_sizes, int n_in,
                              void* d_out, int out_size, void* d_ws, size_t ws_size,
                              hipStream_t stream) {
  const float* x      = (const float*)d_in[0];
  const float* w_qkv  = (const float*)d_in[1];
  const float* w_proj = (const float*)d_in[2];
  float* out = (float*)d_out;
  char* ws = (char*)d_ws;

  unsigned short* xb     = (unsigned short*)(ws);              // 8 MB (reused as ao)
  unsigned short* wqkvT  = (unsigned short*)(ws + 8388608);    // 6 MB
  unsigned short* wprojT = (unsigned short*)(ws + 14680064);   // 2 MB
  unsigned short* qb     = (unsigned short*)(ws + 16777216);   // 8 MB
  unsigned short* kb     = (unsigned short*)(ws + 25165824);   // 8 MB
  unsigned short* vb     = (unsigned short*)(ws + 33554432);   // 8 MB
  unsigned short* ao     = xb;

  cast_x_kernel<<<4096, 256, 0, stream>>>((const float4*)x, (us4v*)xb);
  transpose_cast_kernel<<<dim3(3 * C_ / 32, C_ / 32), dim3(32, 8), 0, stream>>>(
      w_qkv, wqkvT, C_, 3 * C_);
  transpose_cast_kernel<<<dim3(C_ / 32, C_ / 32), dim3(32, 8), 0, stream>>>(
      w_proj, wprojT, C_, C_);
  gemm_qkv_kernel<<<dim3(3 * C_ / 128, (B_ * T_) / 128), 256, 0, stream>>>(
      xb, wqkvT, qb, kb, vb);
  attn_kernel<<<dim3(16, 32), 512, 0, stream>>>(qb, kb, vb, ao);
  gemm_proj_kernel<<<dim3(C_ / 128, (B_ * T_) / 128), 256, 0, stream>>>(
      ao, wprojT, out);
}

// Round 4
// 143.232 us; speedup vs baseline: 1.6291x; 1.1544x over previous
//
#include <hip/hip_runtime.h>
#include <hip/hip_bf16.h>
#include <stdint.h>

typedef __bf16 bf16x8 __attribute__((ext_vector_type(8)));
typedef float f32x4 __attribute__((ext_vector_type(4)));
typedef unsigned short us4v __attribute__((ext_vector_type(4)));
typedef unsigned short us8v __attribute__((ext_vector_type(8)));

#define B_   2
#define T_   2048
#define C_   1024
#define NH_  16
#define HD_  64

__device__ __forceinline__ unsigned short f2bf(float f) {
  unsigned int u = __builtin_bit_cast(unsigned int, f);
  u += 0x7fffu + ((u >> 16) & 1u);           // RNE
  return (unsigned short)(u >> 16);
}
__device__ __forceinline__ float bf2f(unsigned short u) {
  unsigned int x = ((unsigned int)u) << 16;
  return __builtin_bit_cast(float, x);
}

__device__ __forceinline__ void gload16(const void* g, void* l) {
  __builtin_amdgcn_global_load_lds(
      (const __attribute__((address_space(1))) unsigned int*)g,
      (__attribute__((address_space(3))) unsigned int*)l, 16, 0, 0);
}

__device__ __forceinline__ f32x4 mfma16(bf16x8 a, bf16x8 b, f32x4 c) {
  return __builtin_amdgcn_mfma_f32_16x16x32_bf16(a, b, c, 0, 0, 0);
}

// ---------------- cast / transpose ----------------
__global__ __launch_bounds__(256) void cast_x_kernel(const float4* __restrict__ in,
                                                     us4v* __restrict__ out) {
  int i = blockIdx.x * 256 + threadIdx.x;
  float4 f = in[i];
  us4v o; o[0] = f2bf(f.x); o[1] = f2bf(f.y); o[2] = f2bf(f.z); o[3] = f2bf(f.w);
  out[i] = o;
}

// w: (K x N) fp32 row-major  ->  wT: (N x K) bf16 row-major
__global__ __launch_bounds__(256) void transpose_cast_kernel(const float* __restrict__ w,
                                                             unsigned short* __restrict__ wT,
                                                             int K, int N) {
  __shared__ float tile[32][33];
  int n0 = blockIdx.x * 32, k0 = blockIdx.y * 32;
  int tx = threadIdx.x, ty = threadIdx.y;   // 32 x 8
  #pragma unroll
  for (int i = 0; i < 4; ++i)
    tile[ty + 8*i][tx] = w[(size_t)(k0 + ty + 8*i) * N + n0 + tx];
  __syncthreads();
  #pragma unroll
  for (int i = 0; i < 4; ++i)
    wT[(size_t)(n0 + ty + 8*i) * K + k0 + tx] = f2bf(tile[tx][ty + 8*i]);
}

// ---------------- GEMM core (verified round 0) ----------------
__device__ __forceinline__ void gemm_core(const unsigned short* __restrict__ A,
                                          const unsigned short* __restrict__ Bt,
                                          int K, int m0, int n0,
                                          unsigned short* lA, unsigned short* lB,
                                          f32x4 acc[4][4]) {
  const int t = threadIdx.x;
  const int lane = t & 63, w = t >> 6;
  const int wm = w >> 1, wn = w & 1;
  const int g = lane >> 4, r16 = lane & 15;
  #pragma unroll
  for (int i = 0; i < 4; ++i)
    #pragma unroll
    for (int j = 0; j < 4; ++j) acc[i][j] = (f32x4){0.f, 0.f, 0.f, 0.f};

  for (int k0 = 0; k0 < K; k0 += 64) {
    #pragma unroll
    for (int i = 0; i < 4; ++i) {
      int slot = i * 256 + t;
      int r = slot >> 3, p = slot & 7;
      int q = p ^ (r & 7);
      gload16(A  + (size_t)(m0 + r) * K + k0 + q * 8, lA + slot * 8);
      gload16(Bt + (size_t)(n0 + r) * K + k0 + q * 8, lB + slot * 8);
    }
    asm volatile("s_waitcnt vmcnt(0)" ::: "memory");
    __syncthreads();

    bf16x8 af[4][2], bfr[4][2];
    #pragma unroll
    for (int mi = 0; mi < 4; ++mi)
      #pragma unroll
      for (int kk = 0; kk < 2; ++kk) {
        int r = wm * 64 + mi * 16 + r16;
        int ps = (kk * 4 + g) ^ (r & 7);
        af[mi][kk] = *(const bf16x8*)(lA + r * 64 + ps * 8);
      }
    #pragma unroll
    for (int ni = 0; ni < 4; ++ni)
      #pragma unroll
      for (int kk = 0; kk < 2; ++kk) {
        int r = wn * 64 + ni * 16 + r16;
        int ps = (kk * 4 + g) ^ (r & 7);
        bfr[ni][kk] = *(const bf16x8*)(lB + r * 64 + ps * 8);
      }
    #pragma unroll
    for (int mi = 0; mi < 4; ++mi)
      #pragma unroll
      for (int ni = 0; ni < 4; ++ni)
        #pragma unroll
        for (int kk = 0; kk < 2; ++kk)
          acc[mi][ni] = mfma16(af[mi][kk], bfr[ni][kk], acc[mi][ni]);
    __syncthreads();
  }
}

__global__ __launch_bounds__(256) void gemm_qkv_kernel(const unsigned short* __restrict__ xb,
                                                       const unsigned short* __restrict__ wT,
                                                       unsigned short* __restrict__ qb,
                                                       unsigned short* __restrict__ kb,
                                                       unsigned short* __restrict__ vb) {
  __shared__ unsigned short lA[128 * 64];
  __shared__ unsigned short lB[128 * 64];
  f32x4 acc[4][4];
  const int m0 = blockIdx.y * 128, n0 = blockIdx.x * 128;
  gemm_core(xb, wT, C_, m0, n0, lA, lB, acc);
  const int t = threadIdx.x, lane = t & 63, w = t >> 6;
  const int wm = w >> 1, wn = w & 1, g = lane >> 4, r16 = lane & 15;
  #pragma unroll
  for (int mi = 0; mi < 4; ++mi)
    #pragma unroll
    for (int ni = 0; ni < 4; ++ni)
      #pragma unroll
      for (int j = 0; j < 4; ++j) {
        int gm = m0 + wm * 64 + mi * 16 + g * 4 + j;
        int gn = n0 + wn * 64 + ni * 16 + r16;
        int b = gm >> 11, tt = gm & 2047;
        int s = gn >> 10, rem = gn & 1023;
        int h = rem >> 6, d = rem & 63;
        unsigned short val = f2bf(acc[mi][ni][j]);
        size_t idx = ((size_t)(b * NH_ + h) * T_ + tt) * HD_ + d;
        if (s == 0)      qb[idx] = val;
        else if (s == 1) kb[idx] = val;
        else             vb[idx] = val;
      }
}

__global__ __launch_bounds__(256) void gemm_proj_kernel(const unsigned short* __restrict__ ab,
                                                        const unsigned short* __restrict__ wT,
                                                        float* __restrict__ out) {
  __shared__ unsigned short lA[128 * 64];
  __shared__ unsigned short lB[128 * 64];
  f32x4 acc[4][4];
  const int m0 = blockIdx.y * 128, n0 = blockIdx.x * 128;
  gemm_core(ab, wT, C_, m0, n0, lA, lB, acc);
  const int t = threadIdx.x, lane = t & 63, w = t >> 6;
  const int wm = w >> 1, wn = w & 1, g = lane >> 4, r16 = lane & 15;
  #pragma unroll
  for (int mi = 0; mi < 4; ++mi)
    #pragma unroll
    for (int ni = 0; ni < 4; ++ni)
      #pragma unroll
      for (int j = 0; j < 4; ++j) {
        int gm = m0 + wm * 64 + mi * 16 + g * 4 + j;
        int gn = n0 + wn * 64 + ni * 16 + r16;
        out[(size_t)gm * C_ + gn] = acc[mi][ni][j];
      }
}

// ---------------- Flash attention v4 ----------------
// Balanced pairs; swapped QK^T (S^T = mfma(K,Q)) so softmax rows are lane-local;
// P^T kept in registers (B-operand, k-perm lambda(8g+u)=32kk+16(u>>2)+4g+(u&3));
// V staged into column-permuted Vt[d][col'] (col'=32a+8g+4h+e) with b128-slot
// XOR swizzle so the matching V^T A-fragment is one swizzled ds_read_b128.
// LDS (us): K0 [0,4096) K1 [4096,8192) V0 [8192,12288) V1 [12288,16384).
// Epilogue reuses the dead double-buffer half.
__global__ __launch_bounds__(512, 6) void attn_kernel(const unsigned short* __restrict__ qb,
                                                      const unsigned short* __restrict__ kb,
                                                      const unsigned short* __restrict__ vb,
                                                      unsigned short* __restrict__ ao) {
  __shared__ unsigned short LDS[16384];
  const int pairIdx = blockIdx.x, bh = blockIdx.y;
  const int t = threadIdx.x, lane = t & 63, w = t >> 6;
  const int g = lane >> 4, r16 = lane & 15;
  const int ws = w & 3, sel = w >> 2;
  const int qt0 = (sel ? (31 - pairIdx) : pairIdx) * 64;
  const int myNt = (qt0 >> 6) + 1;
  const int ntMax = 32 - pairIdx;

  const unsigned short* Q  = qb + (size_t)bh * (T_ * HD_);
  const unsigned short* Kp = kb + (size_t)bh * (T_ * HD_);
  const unsigned short* Vp = vb + (size_t)bh * (T_ * HD_);

  // Q fragments (PV/QK B-operand layout: lane holds Q[q=r16][k-octet g]),
  // pre-scaled by 1/8 (exact in bf16)
  bf16x8 qf[2];
  {
    int qrow = qt0 + ws * 16 + r16;
    #pragma unroll
    for (int kk = 0; kk < 2; ++kk) {
      us8v raw = *(const us8v*)(Q + (size_t)qrow * HD_ + kk * 32 + g * 8);
      bf16x8 qv;
      #pragma unroll
      for (int j = 0; j < 8; ++j) qv[j] = (__bf16)(bf2f(raw[j]) * 0.125f);
      qf[kk] = qv;
    }
  }

  f32x4 o[4];
  #pragma unroll
  for (int c = 0; c < 4; ++c) o[c] = (f32x4){0.f, 0.f, 0.f, 0.f};
  float mrun = -__builtin_inff(), lrun = 0.f;

  // staging constants
  const int kr = t >> 3, kp = (t & 7) ^ (kr & 7);   // K row / swizzled granule
  const int sV = t >> 3, d0V = (t & 7) * 8;         // V kv-row / d-octet
  // col'(sV) = 32a + 8g' + 4h + e  for sV = 32a + 16h + 4g' + e
  const int colp = (sV & 32) | ((sV & 12) << 1) | ((sV >> 2) & 4) | (sV & 3);
  const int cslot = colp >> 3, cwithin = colp & 7;

  // prologue: tile-0 loads
  gload16(Kp + (size_t)kr * HD_ + kp * 8, LDS + t * 8);
  us8v vrA = *(const us8v*)(Vp + (size_t)sV * HD_ + d0V);
  us8v vrB;

  for (int it = 0; it < ntMax; ++it) {
    const int cur = it & 1;
    const unsigned short* Kl = LDS + cur * 4096;
    unsigned short* Vt = LDS + 8192 + cur * 4096;

    asm volatile("s_waitcnt vmcnt(0)" ::: "memory");   // K[it] in LDS, V[it] in regs
    {
      us8v vv = cur ? vrB : vrA;
      #pragma unroll
      for (int jj = 0; jj < 8; ++jj) {
        int d = d0V + jj;
        Vt[d * 64 + ((cslot ^ jj) << 3) + cwithin] = vv[jj];
      }
    }
    __syncthreads();

    if (it + 1 < ntMax) {    // issue next-tile loads (land in buf cur^1)
      const int kv0n = (it + 1) * 64;
      gload16(Kp + (size_t)(kv0n + kr) * HD_ + kp * 8, LDS + (cur ^ 1) * 4096 + t * 8);
      us8v nv = *(const us8v*)(Vp + (size_t)(kv0n + sV) * HD_ + d0V);
      if (cur) vrA = nv; else vrB = nv;
    }

    if (it < myNt) {
      // S^T = K @ Q^T : s4t[c][j] = S[q=r16][kv = it*64 + 16c + 4g + j]
      f32x4 s4t[4];
      #pragma unroll
      for (int c = 0; c < 4; ++c) s4t[c] = (f32x4){0.f, 0.f, 0.f, 0.f};
      #pragma unroll
      for (int c = 0; c < 4; ++c)
        #pragma unroll
        for (int kk = 0; kk < 2; ++kk) {
          int r = c * 16 + r16;
          int ps = (kk * 4 + g) ^ (r & 7);
          bf16x8 kf = *(const bf16x8*)(Kl + r * 64 + ps * 8);
          s4t[c] = mfma16(kf, qf[kk], s4t[c]);
        }
      if (it == myNt - 1) {   // diagonal tile (kv0 == qt0): mask kv_local > q_local
        int qloc = ws * 16 + r16;
        #pragma unroll
        for (int c = 0; c < 4; ++c)
          #pragma unroll
          for (int j = 0; j < 4; ++j)
            if (c * 16 + g * 4 + j > qloc) s4t[c][j] = -1e30f;
      }
      // online softmax: row q=r16 lane-local across 16 regs + 4 lanes (xor 16,32)
      float mx = -1e30f;
      #pragma unroll
      for (int c = 0; c < 4; ++c)
        #pragma unroll
        for (int j = 0; j < 4; ++j) mx = fmaxf(mx, s4t[c][j]);
      mx = fmaxf(mx, __shfl_xor(mx, 16));
      mx = fmaxf(mx, __shfl_xor(mx, 32));
      float mn = fmaxf(mrun, mx);
      float alpha = __expf(mrun - mn);
      mrun = mn;
      float rs = 0.f;
      #pragma unroll
      for (int c = 0; c < 4; ++c)
        #pragma unroll
        for (int j = 0; j < 4; ++j) {
          float p = __expf(s4t[c][j] - mn);
          s4t[c][j] = p;
          rs += p;
        }
      rs += __shfl_xor(rs, 16);
      rs += __shfl_xor(rs, 32);
      lrun = lrun * alpha + rs;
      #pragma unroll
      for (int c = 0; c < 4; ++c)
        #pragma unroll
        for (int j = 0; j < 4; ++j) o[c][j] *= alpha;

      // P^T fragments in-register (B-operand): p[4h+e] = s4t[2kk+h][e]
      bf16x8 pf[2];
      #pragma unroll
      for (int kk = 0; kk < 2; ++kk) {
        bf16x8 p;
        #pragma unroll
        for (int j = 0; j < 4; ++j) {
          p[j]     = (__bf16)s4t[2 * kk][j];
          p[4 + j] = (__bf16)s4t[2 * kk + 1][j];
        }
        pf[kk] = p;
      }
      // O^T += V^T @ P^T : A-fragment = swizzled b128 from Vt
      #pragma unroll
      for (int c = 0; c < 4; ++c) {
        int rv = c * 16 + r16;
        #pragma unroll
        for (int kk = 0; kk < 2; ++kk) {
          int slot = (4 * kk + g) ^ (r16 & 7);
          bf16x8 vf = *(const bf16x8*)(Vt + rv * 64 + slot * 8);
          o[c] = mfma16(vf, pf[kk], o[c]);
        }
      }
    }
  }

  // epilogue: O[q=r16][d=16c+4g+j] / lrun -> dead-buffer LDS transpose -> store
  const int deadbuf = ntMax & 1;
  unsigned short* ep = (w < 4)
      ? (LDS + deadbuf * 4096 + w * 1024)
      : (LDS + 8192 + deadbuf * 4096 + (w - 4) * 1024);
  float inv = 1.f / lrun;
  #pragma unroll
  for (int c = 0; c < 4; ++c) {
    us4v pk;
    #pragma unroll
    for (int j = 0; j < 4; ++j) pk[j] = f2bf(o[c][j] * inv);
    int slot = (4 * c + g) ^ r16;
    *(us4v*)(ep + r16 * 64 + slot * 4) = pk;
  }
  asm volatile("s_waitcnt lgkmcnt(0)" ::: "memory");
  __builtin_amdgcn_sched_barrier(0);
  {
    int q = lane >> 2, seg = lane & 3;
    us4v a0 = *(const us4v*)(ep + q * 64 + (((seg * 4 + 0) ^ q) & 15) * 4);
    us4v a1 = *(const us4v*)(ep + q * 64 + (((seg * 4 + 1) ^ q) & 15) * 4);
    us4v a2 = *(const us4v*)(ep + q * 64 + (((seg * 4 + 2) ^ q) & 15) * 4);
    us4v a3 = *(const us4v*)(ep + q * 64 + (((seg * 4 + 3) ^ q) & 15) * 4);
    us8v o0 = {a0[0],a0[1],a0[2],a0[3],a1[0],a1[1],a1[2],a1[3]};
    us8v o1 = {a2[0],a2[1],a2[2],a2[3],a3[0],a3[1],a3[2],a3[3]};
    size_t rowg = (size_t)(bh >> 4) * T_ + qt0 + ws * 16 + q;
    int colg = (bh & 15) * 64 + seg * 16;
    *(us8v*)(ao + rowg * C_ + colg)     = o0;
    *(us8v*)(ao + rowg * C_ + colg + 8) = o1;
  }
}

// ---------------- launch ----------------
extern "C" void kernel_launch(void* const* d_in, const int* in_sizes, int n_in,
                              void* d_out, int out_size, void* d_ws, size_t ws_size,
                              hipStream_t stream) {
  const float* x      = (const float*)d_in[0];
  const float* w_qkv  = (const float*)d_in[1];
  const float* w_proj = (const float*)d_in[2];
  float* out = (float*)d_out;
  char* ws = (char*)d_ws;

  unsigned short* xb     = (unsigned short*)(ws);              // 8 MB (reused as ao)
  unsigned short* wqkvT  = (unsigned short*)(ws + 8388608);    // 6 MB
  unsigned short* wprojT = (unsigned short*)(ws + 14680064);   // 2 MB
  unsigned short* qb     = (unsigned short*)(ws + 16777216);   // 8 MB
  unsigned short* kb     = (unsigned short*)(ws + 25165824);   // 8 MB
  unsigned short* vb     = (unsigned short*)(ws + 33554432);   // 8 MB
  unsigned short* ao     = xb;

  cast_x_kernel<<<4096, 256, 0, stream>>>((const float4*)x, (us4v*)xb);
  transpose_cast_kernel<<<dim3(3 * C_ / 32, C_ / 32), dim3(32, 8), 0, stream>>>(
      w_qkv, wqkvT, C_, 3 * C_);
  transpose_cast_kernel<<<dim3(C_ / 32, C_ / 32), dim3(32, 8), 0, stream>>>(
      w_proj, wprojT, C_, C_);
  gemm_qkv_kernel<<<dim3(3 * C_ / 128, (B_ * T_) / 128), 256, 0, stream>>>(
      xb, wqkvT, qb, kb, vb);
  attn_kernel<<<dim3(16, 32), 512, 0, stream>>>(qb, kb, vb, ao);
  gemm_proj_kernel<<<dim3(C_ / 128, (B_ * T_) / 128), 256, 0, stream>>>(
      ao, wprojT, out);
}

// Round 5
// 131.110 us; speedup vs baseline: 1.7797x; 1.0925x over previous
//
#include <hip/hip_runtime.h>
#include <hip/hip_bf16.h>
#include <stdint.h>

typedef __bf16 bf16x8 __attribute__((ext_vector_type(8)));
typedef float f32x4 __attribute__((ext_vector_type(4)));
typedef unsigned short us4v __attribute__((ext_vector_type(4)));
typedef unsigned short us8v __attribute__((ext_vector_type(8)));

#define B_   2
#define T_   2048
#define C_   1024
#define NH_  16
#define HD_  64

__device__ __forceinline__ unsigned short f2bf(float f) {
  unsigned int u = __builtin_bit_cast(unsigned int, f);
  u += 0x7fffu + ((u >> 16) & 1u);           // RNE
  return (unsigned short)(u >> 16);
}
__device__ __forceinline__ float bf2f(unsigned short u) {
  unsigned int x = ((unsigned int)u) << 16;
  return __builtin_bit_cast(float, x);
}

__device__ __forceinline__ void gload16(const void* g, void* l) {
  __builtin_amdgcn_global_load_lds(
      (const __attribute__((address_space(1))) unsigned int*)g,
      (__attribute__((address_space(3))) unsigned int*)l, 16, 0, 0);
}

__device__ __forceinline__ f32x4 mfma16(bf16x8 a, bf16x8 b, f32x4 c) {
  return __builtin_amdgcn_mfma_f32_16x16x32_bf16(a, b, c, 0, 0, 0);
}

// ---------------- cast / transpose ----------------
__global__ __launch_bounds__(256) void cast_x_kernel(const float4* __restrict__ in,
                                                     us4v* __restrict__ out) {
  int i = blockIdx.x * 256 + threadIdx.x;
  float4 f = in[i];
  us4v o; o[0] = f2bf(f.x); o[1] = f2bf(f.y); o[2] = f2bf(f.z); o[3] = f2bf(f.w);
  out[i] = o;
}

// w: (K x N) fp32 row-major  ->  wT: (N x K) bf16 row-major
__global__ __launch_bounds__(256) void transpose_cast_kernel(const float* __restrict__ w,
                                                             unsigned short* __restrict__ wT,
                                                             int K, int N) {
  __shared__ float tile[32][33];
  int n0 = blockIdx.x * 32, k0 = blockIdx.y * 32;
  int tx = threadIdx.x, ty = threadIdx.y;   // 32 x 8
  #pragma unroll
  for (int i = 0; i < 4; ++i)
    tile[ty + 8*i][tx] = w[(size_t)(k0 + ty + 8*i) * N + n0 + tx];
  __syncthreads();
  #pragma unroll
  for (int i = 0; i < 4; ++i)
    wT[(size_t)(n0 + ty + 8*i) * K + k0 + tx] = f2bf(tile[tx][ty + 8*i]);
}

// ---------------- GEMM core (verified round 0) ----------------
__device__ __forceinline__ void gemm_core(const unsigned short* __restrict__ A,
                                          const unsigned short* __restrict__ Bt,
                                          int K, int m0, int n0,
                                          unsigned short* lA, unsigned short* lB,
                                          f32x4 acc[4][4]) {
  const int t = threadIdx.x;
  const int lane = t & 63, w = t >> 6;
  const int wm = w >> 1, wn = w & 1;
  const int g = lane >> 4, r16 = lane & 15;
  #pragma unroll
  for (int i = 0; i < 4; ++i)
    #pragma unroll
    for (int j = 0; j < 4; ++j) acc[i][j] = (f32x4){0.f, 0.f, 0.f, 0.f};

  for (int k0 = 0; k0 < K; k0 += 64) {
    #pragma unroll
    for (int i = 0; i < 4; ++i) {
      int slot = i * 256 + t;
      int r = slot >> 3, p = slot & 7;
      int q = p ^ (r & 7);
      gload16(A  + (size_t)(m0 + r) * K + k0 + q * 8, lA + slot * 8);
      gload16(Bt + (size_t)(n0 + r) * K + k0 + q * 8, lB + slot * 8);
    }
    asm volatile("s_waitcnt vmcnt(0)" ::: "memory");
    __syncthreads();

    bf16x8 af[4][2], bfr[4][2];
    #pragma unroll
    for (int mi = 0; mi < 4; ++mi)
      #pragma unroll
      for (int kk = 0; kk < 2; ++kk) {
        int r = wm * 64 + mi * 16 + r16;
        int ps = (kk * 4 + g) ^ (r & 7);
        af[mi][kk] = *(const bf16x8*)(lA + r * 64 + ps * 8);
      }
    #pragma unroll
    for (int ni = 0; ni < 4; ++ni)
      #pragma unroll
      for (int kk = 0; kk < 2; ++kk) {
        int r = wn * 64 + ni * 16 + r16;
        int ps = (kk * 4 + g) ^ (r & 7);
        bfr[ni][kk] = *(const bf16x8*)(lB + r * 64 + ps * 8);
      }
    #pragma unroll
    for (int mi = 0; mi < 4; ++mi)
      #pragma unroll
      for (int ni = 0; ni < 4; ++ni)
        #pragma unroll
        for (int kk = 0; kk < 2; ++kk)
          acc[mi][ni] = mfma16(af[mi][kk], bfr[ni][kk], acc[mi][ni]);
    __syncthreads();
  }
}

// XCD-aware bijective swizzle of the linear workgroup id (nwg % 8 == 0)
__device__ __forceinline__ int xcd_swz(int flat, int nwg) {
  int cpx = nwg >> 3;
  return (flat & 7) * cpx + (flat >> 3);
}

__global__ __launch_bounds__(256) void gemm_qkv_kernel(const unsigned short* __restrict__ xb,
                                                       const unsigned short* __restrict__ wT,
                                                       unsigned short* __restrict__ qb,
                                                       unsigned short* __restrict__ kb,
                                                       unsigned short* __restrict__ vb) {
  __shared__ unsigned short lA[128 * 64];
  __shared__ unsigned short lB[128 * 64];
  f32x4 acc[4][4];
  const int nbx = 3 * C_ / 128;
  int flat = xcd_swz(blockIdx.y * nbx + blockIdx.x, nbx * ((B_ * T_) / 128));
  const int m0 = (flat / nbx) * 128, n0 = (flat % nbx) * 128;
  gemm_core(xb, wT, C_, m0, n0, lA, lB, acc);
  const int t = threadIdx.x, lane = t & 63, w = t >> 6;
  const int wm = w >> 1, wn = w & 1, g = lane >> 4, r16 = lane & 15;
  #pragma unroll
  for (int mi = 0; mi < 4; ++mi)
    #pragma unroll
    for (int ni = 0; ni < 4; ++ni)
      #pragma unroll
      for (int j = 0; j < 4; ++j) {
        int gm = m0 + wm * 64 + mi * 16 + g * 4 + j;
        int gn = n0 + wn * 64 + ni * 16 + r16;
        int b = gm >> 11, tt = gm & 2047;
        int s = gn >> 10, rem = gn & 1023;
        int h = rem >> 6, d = rem & 63;
        unsigned short val = f2bf(acc[mi][ni][j]);
        size_t idx = ((size_t)(b * NH_ + h) * T_ + tt) * HD_ + d;
        if (s == 0)      qb[idx] = val;
        else if (s == 1) kb[idx] = val;
        else             vb[idx] = val;
      }
}

__global__ __launch_bounds__(256) void gemm_proj_kernel(const unsigned short* __restrict__ ab,
                                                        const unsigned short* __restrict__ wT,
                                                        float* __restrict__ out) {
  __shared__ unsigned short lA[128 * 64];
  __shared__ unsigned short lB[128 * 64];
  f32x4 acc[4][4];
  const int nbx = C_ / 128;
  int flat = xcd_swz(blockIdx.y * nbx + blockIdx.x, nbx * ((B_ * T_) / 128));
  const int m0 = (flat / nbx) * 128, n0 = (flat % nbx) * 128;
  gemm_core(ab, wT, C_, m0, n0, lA, lB, acc);
  const int t = threadIdx.x, lane = t & 63, w = t >> 6;
  const int wm = w >> 1, wn = w & 1, g = lane >> 4, r16 = lane & 15;
  #pragma unroll
  for (int mi = 0; mi < 4; ++mi)
    #pragma unroll
    for (int ni = 0; ni < 4; ++ni)
      #pragma unroll
      for (int j = 0; j < 4; ++j) {
        int gm = m0 + wm * 64 + mi * 16 + g * 4 + j;
        int gn = n0 + wn * 64 + ni * 16 + r16;
        out[(size_t)gm * C_ + gn] = acc[mi][ni][j];
      }
}

// ---------------- Flash attention v5 ----------------
// v4 + conflict-free V staging: wave w owns d-octet [8w,8w+8), lane owns kv row
// `lane`. Each write-step u writes one full 128-B Vt row (colp(lane) bijective
// over 0..63) -> 2 lanes/dword = conflict-free. Read side identical to v4.
__global__ __launch_bounds__(512, 6) void attn_kernel(const unsigned short* __restrict__ qb,
                                                      const unsigned short* __restrict__ kb,
                                                      const unsigned short* __restrict__ vb,
                                                      unsigned short* __restrict__ ao) {
  __shared__ unsigned short LDS[16384];
  const int pairIdx = blockIdx.x, bh = blockIdx.y;
  const int t = threadIdx.x, lane = t & 63, w = t >> 6;
  const int g = lane >> 4, r16 = lane & 15;
  const int ws = w & 3, sel = w >> 2;
  const int qt0 = (sel ? (31 - pairIdx) : pairIdx) * 64;
  const int myNt = (qt0 >> 6) + 1;
  const int ntMax = 32 - pairIdx;

  const unsigned short* Q  = qb + (size_t)bh * (T_ * HD_);
  const unsigned short* Kp = kb + (size_t)bh * (T_ * HD_);
  const unsigned short* Vp = vb + (size_t)bh * (T_ * HD_);

  // Q fragments (B-operand layout: lane holds Q[q=r16][k-octet g]), pre-scaled 1/8
  bf16x8 qf[2];
  {
    int qrow = qt0 + ws * 16 + r16;
    #pragma unroll
    for (int kk = 0; kk < 2; ++kk) {
      us8v raw = *(const us8v*)(Q + (size_t)qrow * HD_ + kk * 32 + g * 8);
      bf16x8 qv;
      #pragma unroll
      for (int j = 0; j < 8; ++j) qv[j] = (__bf16)(bf2f(raw[j]) * 0.125f);
      qf[kk] = qv;
    }
  }

  f32x4 o[4];
  #pragma unroll
  for (int c = 0; c < 4; ++c) o[c] = (f32x4){0.f, 0.f, 0.f, 0.f};
  float mrun = -__builtin_inff(), lrun = 0.f;

  // staging constants
  const int kr = t >> 3, kp = (t & 7) ^ (kr & 7);   // K row / swizzled granule
  // V: wave w owns d-octet w, lane owns kv row `lane`.
  // col'(kv): kv = 32a+16H+4G+E -> col' = 32a+8G+4H+E
  const int colp = (lane & 32) | ((lane & 12) << 1) | ((lane >> 2) & 4) | (lane & 3);
  const int cslot = colp >> 3, cwithin = colp & 7;

  // prologue: tile-0 loads
  gload16(Kp + (size_t)kr * HD_ + kp * 8, LDS + t * 8);
  us8v vrA = *(const us8v*)(Vp + (size_t)lane * HD_ + w * 8);
  us8v vrB;

  for (int it = 0; it < ntMax; ++it) {
    const int cur = it & 1;
    const unsigned short* Kl = LDS + cur * 4096;
    unsigned short* Vt = LDS + 8192 + cur * 4096;

    asm volatile("s_waitcnt vmcnt(0)" ::: "memory");   // K[it] in LDS, V[it] in regs
    {
      us8v vv = cur ? vrB : vrA;
      #pragma unroll
      for (int u = 0; u < 8; ++u) {
        int d = w * 8 + u;                       // d&7 == u
        Vt[d * 64 + ((cslot ^ u) << 3) + cwithin] = vv[u];
      }
    }
    __syncthreads();

    if (it + 1 < ntMax) {    // issue next-tile loads (land in buf cur^1)
      const int kv0n = (it + 1) * 64;
      gload16(Kp + (size_t)(kv0n + kr) * HD_ + kp * 8, LDS + (cur ^ 1) * 4096 + t * 8);
      us8v nv = *(const us8v*)(Vp + (size_t)(kv0n + lane) * HD_ + w * 8);
      if (cur) vrA = nv; else vrB = nv;
    }

    if (it < myNt) {
      // S^T = K @ Q^T : s4t[c][j] = S[q=r16][kv = it*64 + 16c + 4g + j]
      f32x4 s4t[4];
      #pragma unroll
      for (int c = 0; c < 4; ++c) s4t[c] = (f32x4){0.f, 0.f, 0.f, 0.f};
      #pragma unroll
      for (int c = 0; c < 4; ++c)
        #pragma unroll
        for (int kk = 0; kk < 2; ++kk) {
          int r = c * 16 + r16;
          int ps = (kk * 4 + g) ^ (r & 7);
          bf16x8 kf = *(const bf16x8*)(Kl + r * 64 + ps * 8);
          s4t[c] = mfma16(kf, qf[kk], s4t[c]);
        }
      if (it == myNt - 1) {   // diagonal tile (kv0 == qt0): mask kv_local > q_local
        int qloc = ws * 16 + r16;
        #pragma unroll
        for (int c = 0; c < 4; ++c)
          #pragma unroll
          for (int j = 0; j < 4; ++j)
            if (c * 16 + g * 4 + j > qloc) s4t[c][j] = -1e30f;
      }
      // online softmax: row q=r16 lane-local across 16 regs + 4 lanes (xor 16,32)
      float mx = -1e30f;
      #pragma unroll
      for (int c = 0; c < 4; ++c)
        #pragma unroll
        for (int j = 0; j < 4; ++j) mx = fmaxf(mx, s4t[c][j]);
      mx = fmaxf(mx, __shfl_xor(mx, 16));
      mx = fmaxf(mx, __shfl_xor(mx, 32));
      float mn = fmaxf(mrun, mx);
      float alpha = __expf(mrun - mn);
      mrun = mn;
      float rs = 0.f;
      #pragma unroll
      for (int c = 0; c < 4; ++c)
        #pragma unroll
        for (int j = 0; j < 4; ++j) {
          float p = __expf(s4t[c][j] - mn);
          s4t[c][j] = p;
          rs += p;
        }
      rs += __shfl_xor(rs, 16);
      rs += __shfl_xor(rs, 32);
      lrun = lrun * alpha + rs;
      #pragma unroll
      for (int c = 0; c < 4; ++c)
        #pragma unroll
        for (int j = 0; j < 4; ++j) o[c][j] *= alpha;

      // P^T fragments in-register (B-operand): p[4h+e] = s4t[2kk+h][e]
      bf16x8 pf[2];
      #pragma unroll
      for (int kk = 0; kk < 2; ++kk) {
        bf16x8 p;
        #pragma unroll
        for (int j = 0; j < 4; ++j) {
          p[j]     = (__bf16)s4t[2 * kk][j];
          p[4 + j] = (__bf16)s4t[2 * kk + 1][j];
        }
        pf[kk] = p;
      }
      // O^T += V^T @ P^T : A-fragment = swizzled b128 from Vt
      #pragma unroll
      for (int c = 0; c < 4; ++c) {
        int rv = c * 16 + r16;
        #pragma unroll
        for (int kk = 0; kk < 2; ++kk) {
          int slot = (4 * kk + g) ^ (r16 & 7);
          bf16x8 vf = *(const bf16x8*)(Vt + rv * 64 + slot * 8);
          o[c] = mfma16(vf, pf[kk], o[c]);
        }
      }
    }
  }

  // epilogue: O[q=r16][d=16c+4g+j] / lrun -> dead-buffer LDS transpose -> store
  const int deadbuf = ntMax & 1;
  unsigned short* ep = (w < 4)
      ? (LDS + deadbuf * 4096 + w * 1024)
      : (LDS + 8192 + deadbuf * 4096 + (w - 4) * 1024);
  float inv = 1.f / lrun;
  #pragma unroll
  for (int c = 0; c < 4; ++c) {
    us4v pk;
    #pragma unroll
    for (int j = 0; j < 4; ++j) pk[j] = f2bf(o[c][j] * inv);
    int slot = (4 * c + g) ^ r16;
    *(us4v*)(ep + r16 * 64 + slot * 4) = pk;
  }
  asm volatile("s_waitcnt lgkmcnt(0)" ::: "memory");
  __builtin_amdgcn_sched_barrier(0);
  {
    int q = lane >> 2, seg = lane & 3;
    us4v a0 = *(const us4v*)(ep + q * 64 + (((seg * 4 + 0) ^ q) & 15) * 4);
    us4v a1 = *(const us4v*)(ep + q * 64 + (((seg * 4 + 1) ^ q) & 15) * 4);
    us4v a2 = *(const us4v*)(ep + q * 64 + (((seg * 4 + 2) ^ q) & 15) * 4);
    us4v a3 = *(const us4v*)(ep + q * 64 + (((seg * 4 + 3) ^ q) & 15) * 4);
    us8v o0 = {a0[0],a0[1],a0[2],a0[3],a1[0],a1[1],a1[2],a1[3]};
    us8v o1 = {a2[0],a2[1],a2[2],a2[3],a3[0],a3[1],a3[2],a3[3]};
    size_t rowg = (size_t)(bh >> 4) * T_ + qt0 + ws * 16 + q;
    int colg = (bh & 15) * 64 + seg * 16;
    *(us8v*)(ao + rowg * C_ + colg)     = o0;
    *(us8v*)(ao + rowg * C_ + colg + 8) = o1;
  }
}

// ---------------- launch ----------------
extern "C" void kernel_launch(void* const* d_in, const int* in_sizes, int n_in,
                              void* d_out, int out_size, void* d_ws, size_t ws_size,
                              hipStream_t stream) {
  const float* x      = (const float*)d_in[0];
  const float* w_qkv  = (const float*)d_in[1];
  const float* w_proj = (const float*)d_in[2];
  float* out = (float*)d_out;
  char* ws = (char*)d_ws;

  unsigned short* xb     = (unsigned short*)(ws);              // 8 MB (reused as ao)
  unsigned short* wqkvT  = (unsigned short*)(ws + 8388608);    // 6 MB
  unsigned short* wprojT = (unsigned short*)(ws + 14680064);   // 2 MB
  unsigned short* qb     = (unsigned short*)(ws + 16777216);   // 8 MB
  unsigned short* kb     = (unsigned short*)(ws + 25165824);   // 8 MB
  unsigned short* vb     = (unsigned short*)(ws + 33554432);   // 8 MB
  unsigned short* ao     = xb;

  cast_x_kernel<<<4096, 256, 0, stream>>>((const float4*)x, (us4v*)xb);
  transpose_cast_kernel<<<dim3(3 * C_ / 32, C_ / 32), dim3(32, 8), 0, stream>>>(
      w_qkv, wqkvT, C_, 3 * C_);
  transpose_cast_kernel<<<dim3(C_ / 32, C_ / 32), dim3(32, 8), 0, stream>>>(
      w_proj, wprojT, C_, C_);
  gemm_qkv_kernel<<<dim3(3 * C_ / 128, (B_ * T_) / 128), 256, 0, stream>>>(
      xb, wqkvT, qb, kb, vb);
  attn_kernel<<<dim3(16, 32), 512, 0, stream>>>(qb, kb, vb, ao);
  gemm_proj_kernel<<<dim3(C_ / 128, (B_ * T_) / 128), 256, 0, stream>>>(
      ao, wprojT, out);
}